// Round 4
// baseline (43.785 us; speedup 1.0000x reference)
//
#include <hip/hip_runtime.h>
#include <math.h>

// Fused SVD rigid registration: one block (128 threads = 2 waves) per batch.
//  - 2 waves each reduce 1024 points of weighted moments (W, St[3], Ss[3], M[9])
//    with register double-buffered float4 loads (14 loads in flight).
//  - folding wave reduction (17 shuffles), 32-float LDS exchange.
//  - lane 0 of wave 0: cov assembly (double) + det-scaled Newton polar
//    iteration (R = U@Vh of SVD, no sqrt/SVD needed), writes the 4x4 T.

constexpr int BN = 2048;  // points per batch

__global__ __launch_bounds__(128) void svdreg_fused(
    const float* __restrict__ target,
    const float* __restrict__ source,
    const float* __restrict__ weights,
    float* __restrict__ out)
{
    const int lane = threadIdx.x & 63;
    const int wav  = threadIdx.x >> 6;  // 0..1
    const int b    = blockIdx.x;

    constexpr int GROUPS = BN / 4;     // 512 float4-groups (4 points each)
    constexpr int GPW    = GROUPS / 2; // 256 groups per wave
    constexpr int ITERS  = GPW / 64;   // 4 groups per lane

    const float4* t4 = reinterpret_cast<const float4*>(target + (size_t)b * BN * 3);
    const float4* s4 = reinterpret_cast<const float4*>(source + (size_t)b * BN * 3);
    const float4* w4 = reinterpret_cast<const float4*>(weights + (size_t)b * BN);

    // [0]=W, [1..3]=sum w*t, [4..6]=sum w*s, [7..15]=M[i][j]=sum w*t_i*s_j
    float acc[16];
#pragma unroll
    for (int i = 0; i < 16; ++i) acc[i] = 0.f;

    int g = wav * GPW + lane;
    float4 ct0 = t4[g * 3 + 0], ct1 = t4[g * 3 + 1], ct2 = t4[g * 3 + 2];
    float4 cs0 = s4[g * 3 + 0], cs1 = s4[g * 3 + 1], cs2 = s4[g * 3 + 2];
    float4 cwv = w4[g];

#pragma unroll
    for (int it = 0; it < ITERS; ++it) {
        float4 nt0, nt1, nt2, ns0, ns1, ns2, nwv;
        if (it + 1 < ITERS) {  // prefetch next group while computing current
            const int gn = g + 64;
            nt0 = t4[gn * 3 + 0]; nt1 = t4[gn * 3 + 1]; nt2 = t4[gn * 3 + 2];
            ns0 = s4[gn * 3 + 0]; ns1 = s4[gn * 3 + 1]; ns2 = s4[gn * 3 + 2];
            nwv = w4[gn];
        }

        float tx[4] = {ct0.x, ct0.w, ct1.z, ct2.y};
        float ty[4] = {ct0.y, ct1.x, ct1.w, ct2.z};
        float tz[4] = {ct0.z, ct1.y, ct2.x, ct2.w};
        float sx[4] = {cs0.x, cs0.w, cs1.z, cs2.y};
        float sy[4] = {cs0.y, cs1.x, cs1.w, cs2.z};
        float sz[4] = {cs0.z, cs1.y, cs2.x, cs2.w};
        float ww[4] = {cwv.x, cwv.y, cwv.z, cwv.w};

#pragma unroll
        for (int j = 0; j < 4; ++j) {
            float w = ww[j];
            acc[0] += w;
            float wtx = w * tx[j], wty = w * ty[j], wtz = w * tz[j];
            acc[1] += wtx;  acc[2] += wty;  acc[3] += wtz;
            acc[4] += w * sx[j]; acc[5] += w * sy[j]; acc[6] += w * sz[j];
            acc[7]  += wtx * sx[j]; acc[8]  += wtx * sy[j]; acc[9]  += wtx * sz[j];
            acc[10] += wty * sx[j]; acc[11] += wty * sy[j]; acc[12] += wty * sz[j];
            acc[13] += wtz * sx[j]; acc[14] += wtz * sy[j]; acc[15] += wtz * sz[j];
        }

        ct0 = nt0; ct1 = nt1; ct2 = nt2;
        cs0 = ns0; cs1 = ns1; cs2 = ns2;
        cwv = nwv; g += 64;
    }

    // Folding multi-value wave reduction: 16 -> 8 -> 4 -> 2 -> 1 values,
    // then 2 butterfly steps. 17 shuffles total, all statically indexed.
    {
        const bool u5 = (lane & 32) != 0;
#pragma unroll
        for (int v = 0; v < 8; ++v) {
            float send = u5 ? acc[v] : acc[v + 8];
            float r = __shfl_xor(send, 32);
            acc[v] = (u5 ? acc[v + 8] : acc[v]) + r;
        }
        const bool u4 = (lane & 16) != 0;
#pragma unroll
        for (int v = 0; v < 4; ++v) {
            float send = u4 ? acc[v] : acc[v + 4];
            float r = __shfl_xor(send, 16);
            acc[v] = (u4 ? acc[v + 4] : acc[v]) + r;
        }
        const bool u3 = (lane & 8) != 0;
#pragma unroll
        for (int v = 0; v < 2; ++v) {
            float send = u3 ? acc[v] : acc[v + 2];
            float r = __shfl_xor(send, 8);
            acc[v] = (u3 ? acc[v + 2] : acc[v]) + r;
        }
        const bool u2 = (lane & 4) != 0;
        {
            float send = u2 ? acc[0] : acc[1];
            float r = __shfl_xor(send, 4);
            acc[0] = (u2 ? acc[1] : acc[0]) + r;
        }
        acc[0] += __shfl_xor(acc[0], 2);
        acc[0] += __shfl_xor(acc[0], 1);
    }

    // lane -> moment index (from the keep/send pattern): bit5->3,4->2,3->1,2->0
    __shared__ float part[2][16];
    const int aidx = (((lane >> 5) & 1) << 3) | (((lane >> 4) & 1) << 2) |
                     (((lane >> 3) & 1) << 1) | ((lane >> 2) & 1);
    if ((lane & 3) == 0) part[wav][aidx] = acc[0];
    __syncthreads();

    if (threadIdx.x != 0) return;

    // ---- serial tail on lane 0 of wave 0 (overlaps other blocks' mem phases)
    double v[16];
#pragma unroll
    for (int i = 0; i < 16; ++i)
        v[i] = (double)part[0][i] + (double)part[1][i];

    const double W  = v[0];
    const double Wd = W + 1e-8;
    double St[3] = {v[1], v[2], v[3]};
    double Ss[3] = {v[4], v[5], v[6]};
    double mt[3], ms[3];
#pragma unroll
    for (int i = 0; i < 3; ++i) { mt[i] = St[i] / Wd; ms[i] = Ss[i] / Wd; }

    double A[3][3];
#pragma unroll
    for (int i = 0; i < 3; ++i)
#pragma unroll
        for (int j = 0; j < 3; ++j)
            A[i][j] = v[7 + i * 3 + j] - mt[i] * Ss[j] - ms[j] * St[i] + mt[i] * ms[j] * W;

    // Det-scaled Newton polar iteration:
    //   X <- 0.5*(mu*X + (1/(mu*det))*cof(X))  ->  orthogonal polar factor U@Vh
    double X[3][3];
#pragma unroll
    for (int i = 0; i < 3; ++i)
#pragma unroll
        for (int j = 0; j < 3; ++j) X[i][j] = A[i][j];

#pragma unroll
    for (int iter = 0; iter < 10; ++iter) {
        double C[3][3];
        C[0][0] = X[1][1]*X[2][2] - X[1][2]*X[2][1];
        C[0][1] = X[1][2]*X[2][0] - X[1][0]*X[2][2];
        C[0][2] = X[1][0]*X[2][1] - X[1][1]*X[2][0];
        C[1][0] = X[0][2]*X[2][1] - X[0][1]*X[2][2];
        C[1][1] = X[0][0]*X[2][2] - X[0][2]*X[2][0];
        C[1][2] = X[0][1]*X[2][0] - X[0][0]*X[2][1];
        C[2][0] = X[0][1]*X[1][2] - X[0][2]*X[1][1];
        C[2][1] = X[0][2]*X[1][0] - X[0][0]*X[1][2];
        C[2][2] = X[0][0]*X[1][1] - X[0][1]*X[1][0];
        double det = X[0][0]*C[0][0] + X[0][1]*C[0][1] + X[0][2]*C[0][2];
        double ad  = fabs(det);
        if (!(ad > 1e-300)) { det = (det >= 0.0) ? 1e-300 : -1e-300; ad = 1e-300; }

        double mu = 1.0;
        if (iter < 6) {  // det^{-1/3} scaling accelerates early phase
            float adf = (float)ad;
            if (adf > 0.f && isfinite(adf))
                mu = (double)exp2f(-log2f(adf) * (1.0f / 3.0f));
        }
        double k1 = 0.5 * mu;
        double k2 = 0.5 / (mu * det);
#pragma unroll
        for (int i = 0; i < 3; ++i)
#pragma unroll
            for (int j = 0; j < 3; ++j)
                X[i][j] = k1 * X[i][j] + k2 * C[i][j];
    }

    double tvec[3];
#pragma unroll
    for (int i = 0; i < 3; ++i) {
        double s = mt[i];
#pragma unroll
        for (int k = 0; k < 3; ++k) s -= X[i][k] * ms[k];
        tvec[i] = s;
    }

    float4* o = reinterpret_cast<float4*>(out + (size_t)b * 16);
    o[0] = make_float4((float)X[0][0], (float)X[0][1], (float)X[0][2], (float)tvec[0]);
    o[1] = make_float4((float)X[1][0], (float)X[1][1], (float)X[1][2], (float)tvec[1]);
    o[2] = make_float4((float)X[2][0], (float)X[2][1], (float)X[2][2], (float)tvec[2]);
    o[3] = make_float4(0.f, 0.f, 0.f, 1.f);
}

extern "C" void kernel_launch(void* const* d_in, const int* in_sizes, int n_in,
                              void* d_out, int out_size, void* d_ws, size_t ws_size,
                              hipStream_t stream) {
    const float* target  = (const float*)d_in[0];
    const float* source  = (const float*)d_in[1];
    const float* weights = (const float*)d_in[2];
    float* out = (float*)d_out;

    const int B = in_sizes[2] / BN;  // weights flat = B*N
    svdreg_fused<<<B, 128, 0, stream>>>(target, source, weights, out);
}